// Round 1
// baseline (3631.337 us; speedup 1.0000x reference)
//
#include <hip/hip_runtime.h>
#include <hip/hip_bf16.h>

using bf16 = __hip_bfloat16;
typedef __attribute__((ext_vector_type(8))) short bfrag;   // 8 bf16 (4 VGPRs)
typedef __attribute__((ext_vector_type(4))) float ffrag;   // 4 fp32 acc

constexpr int kH  = 32;    // hidden
constexpr int kE  = 64;    // embed
constexpr int kV  = 258;   // vocab
constexpr int kB  = 16;    // batch
constexpr int kR  = 64;    // rows
constexpr int kS  = 64;    // cols
constexpr int kG  = 96;    // 3*H
constexpr int kEP = 65;    // E+1

// ---------------- workspace layout (unchanged) ----------------
constexpr int H2_OFF   = (3*kB*kR*kS*kH)/2;
constexpr int PROG_OFF = H2_OFF;                      // legacy progress flags (unused now)
constexpr int T_OFF    = H2_OFF + kB*kR*kH;           // [3][258][96]  emb@Wih0[:, :64].T
constexpr int WPH_OFF  = T_OFF + 3*kV*kG;             // [3][96][32]   Wih0 @ h2e_W  fold
constexpr int WADP_OFF = WPH_OFF + 3*kG*kH;           // [2][96][32]   Wih0 @ adp_W  fold
constexpr int C0_OFF   = WADP_OFF + 2*kG*kH;          // [3][96]
constexpr int RW_OFF   = C0_OFF + 3*kG;               // [3][96]
constexpr int TG_OFF   = RW_OFF + 3*kG;               // [258][258]
constexpr int TBR_OFF  = TG_OFF + kV*kV;              // [258][258]
constexpr int TBG_OFF  = TBR_OFF + kV*kV;             // [258][258]
constexpr int P_EMB    = TBG_OFF + kV*kV;
constexpr int P_WIH0   = P_EMB    + 3*kV*kE;
constexpr int P_WIHR   = P_WIH0   + 3*kG*kEP;
constexpr int P_WHH    = P_WIHR   + 3*2*kG*kH;
constexpr int P_BIH    = P_WHH    + 3*3*kG*kH;
constexpr int P_BHH    = P_BIH    + 3*3*kG;
constexpr int P_H2EW   = P_BHH    + 3*3*kG;
constexpr int P_H2EB   = P_H2EW   + 3*kEP*kH;
constexpr int P_ADPW   = P_H2EB   + 3*kEP;
constexpr int P_ADPB   = P_ADPW   + 2*kEP*kH;
constexpr int P_REDW   = P_ADPB   + 2*kEP;
constexpr int P_REDB   = P_REDW   + kV*kH;
constexpr int P_GREENW = P_REDB   + kV;
constexpr int P_GREENB = P_GREENW + kV*(kH+kE);
constexpr int P_BLUEW  = P_GREENB + kV;
constexpr int P_BLUEB  = P_BLUEW  + kV*(kH+2*kE);
constexpr int WS_END   = P_BLUEB  + kV;               // ~14.0 MB

__device__ __forceinline__ float tof(bf16 h) { return __bfloat162float(h); }

__device__ __forceinline__ unsigned short bfbits(bf16 h) {
  union { bf16 h; unsigned short u; } cv; cv.h = h; return cv.u;
}
__device__ __forceinline__ short f2b(float v) {
  return (short)bfbits(__float2bfloat16(v));
}
__device__ __forceinline__ float sigm(float v) { return 1.0f / (1.0f + __expf(-v)); }
__device__ __forceinline__ float tanh_(float v) { return 1.0f - 2.0f / (__expf(2.0f * v) + 1.0f); }

#define MFMA16(a, bb, cc) __builtin_amdgcn_mfma_f32_16x16x32_bf16((a), (bb), (cc), 0, 0, 0)

// ---------------- dtype detect + normalize to fp32 (unchanged, verified) ----------------
__global__ void norm_kernel(const void* p0, const void* p1, const void* p2, const void* p3,
                            const void* p4, const void* p5, const void* p6, const void* p7,
                            const void* p8, const void* p9, const void* p10, const void* p11,
                            const void* p12, const void* p13, const void* p14, const void* p15,
                            float* __restrict__ wsf)
{
  constexpr int counts[16] = {3*kV*kE, 3*kG*kEP, 3*2*kG*kH, 3*3*kG*kH, 3*3*kG, 3*3*kG,
                              3*kEP*kH, 3*kEP, 2*kEP*kH, 2*kEP, kV*kH, kV,
                              kV*(kH+kE), kV, kV*(kH+2*kE), kV};
  constexpr int dsts[16] = {P_EMB, P_WIH0, P_WIHR, P_WHH, P_BIH, P_BHH,
                            P_H2EW, P_H2EB, P_ADPW, P_ADPB, P_REDW, P_REDB,
                            P_GREENW, P_GREENB, P_BLUEW, P_BLUEB};
  const void* srcs[16] = {p0,p1,p2,p3,p4,p5,p6,p7,p8,p9,p10,p11,p12,p13,p14,p15};

  __shared__ unsigned int smax;
  const int a = blockIdx.x;
  const void* src = srcs[a];
  const int n = counts[a];
  if (threadIdx.x == 0) smax = 0;
  if (a == 0) {
    int* prog = (int*)(wsf + PROG_OFF);
    for (int i = threadIdx.x; i < 48; i += 256) prog[i] = 0;
  }
  __syncthreads();

  const unsigned short* u16 = (const unsigned short*)src;
  const int ns = (n < 2048) ? n : 2048;
  unsigned int lm = 0;
  for (int i = threadIdx.x; i < ns; i += 256) {
    unsigned int e = ((unsigned int)u16[i] >> 7) & 0xFFu;
    if (e > lm) lm = e;
  }
  atomicMax(&smax, lm);
  __syncthreads();

  const bool isf32 = (smax >= 135);
  float* dst = wsf + dsts[a];
  if (isf32) {
    const float* s = (const float*)src;
    for (int i = threadIdx.x; i < n; i += 256) dst[i] = s[i];
  } else {
    const bf16* s = (const bf16*)src;
    for (int i = threadIdx.x; i < n; i += 256) dst[i] = tof(s[i]);
  }
}

// ---------------- prep: fold tables & matrices (unchanged, verified) ----------------
__global__ void prep_kernel(float* __restrict__ wsf)
{
  int idx = blockIdx.x * 256 + threadIdx.x;

  if (idx < 3*kV*kG) {
    int c = idx / (kV*kG);
    int rem = idx - c*(kV*kG);
    int v = rem / kG;
    int j = rem - v*kG;
    const float* ev = wsf + P_EMB + (c*kV + v)*kE;
    const float* wr = wsf + P_WIH0 + (c*kG + j)*kEP;
    float acc = 0.f;
    for (int e = 0; e < kE; ++e) acc = fmaf(ev[e], wr[e], acc);
    wsf[T_OFF + idx] = acc;
    return;
  }
  idx -= 3*kV*kG;

  if (idx < 3*kG*kH) {
    int c = idx / (kG*kH);
    int rem = idx - c*(kG*kH);
    int j = rem >> 5;
    int k = rem & 31;
    const float* wr = wsf + P_WIH0 + (c*kG + j)*kEP;
    const float* hw = wsf + P_H2EW + c*kEP*kH + k;
    float acc = 0.f;
    for (int e = 0; e < kEP; ++e) acc = fmaf(wr[e], hw[e*kH], acc);
    wsf[WPH_OFF + idx] = acc;
    return;
  }
  idx -= 3*kG*kH;

  if (idx < 2*kG*kH) {
    int cm = idx / (kG*kH);
    int rem = idx - cm*(kG*kH);
    int j = rem >> 5;
    int k = rem & 31;
    const float* wr = wsf + P_WIH0 + ((cm+1)*kG + j)*kEP;
    const float* aw = wsf + P_ADPW + cm*kEP*kH + k;
    float acc = 0.f;
    for (int e = 0; e < kEP; ++e) acc = fmaf(wr[e], aw[e*kH], acc);
    wsf[WADP_OFF + idx] = acc;
    return;
  }
  idx -= 2*kG*kH;

  if (idx < 3*kG) {
    int c = idx / kG;
    int j = idx - c*kG;
    const float* wr = wsf + P_WIH0 + (c*kG + j)*kEP;
    float acc = wsf[P_BIH + (c*3 + 0)*kG + j];
    for (int e = 0; e < kEP; ++e) acc = fmaf(wsf[P_H2EB + c*kEP + e], wr[e], acc);
    if (c > 0)
      for (int e = 0; e < kEP; ++e) acc = fmaf(wsf[P_ADPB + (c-1)*kEP + e], wr[e], acc);
    wsf[C0_OFF + idx] = acc;
    return;
  }
  idx -= 3*kG;

  if (idx < 3*kG) {
    int c = idx / kG;
    int j = idx - c*kG;
    wsf[RW_OFF + idx] = wsf[P_WIH0 + (c*kG + j)*kEP + kE];
    return;
  }
  idx -= 3*kG;

  if (idx < kV*kV) {
    int v = idx / kV, w = idx - (idx / kV)*kV;
    const float* ev = wsf + P_EMB + v*kE;
    const float* gw = wsf + P_GREENW + w*(kH + kE) + kH;
    float acc = 0.f;
    for (int e = 0; e < kE; ++e) acc = fmaf(ev[e], gw[e], acc);
    wsf[TG_OFF + idx] = acc;
    return;
  }
  idx -= kV*kV;

  if (idx < kV*kV) {
    int v = idx / kV, w = idx - (idx / kV)*kV;
    const float* ev = wsf + P_EMB + v*kE;
    const float* bw = wsf + P_BLUEW + w*(kH + 2*kE) + kH;
    float acc = 0.f;
    for (int e = 0; e < kE; ++e) acc = fmaf(ev[e], bw[e], acc);
    wsf[TBR_OFF + idx] = acc;
    return;
  }
  idx -= kV*kV;

  if (idx < kV*kV) {
    int v = idx / kV, w = idx - (idx / kV)*kV;
    const float* ev = wsf + P_EMB + (kV + v)*kE;
    const float* bw = wsf + P_BLUEW + w*(kH + 2*kE) + kH + kE;
    float acc = 0.f;
    for (int e = 0; e < kE; ++e) acc = fmaf(ev[e], bw[e], acc);
    wsf[TBG_OFF + idx] = acc;
  }
}

// ---------------- fused 3-channel wavefront recurrence: ONE BLOCK PER BATCH ----------------
// Grid = 16 blocks (one per batch). Block = 384 = 6 waves: wave = c*2 + hw,
// channel c in {0,1,2}, hw = row half (rows [32*hw, 32*hw+32) as two 16-row MFMA chunks).
// All cross-channel handoff via LDS ring buffers + one __syncthreads per diagonal step:
// NO agent fences, NO device atomics, NO spin waits (the old 10.6us/step cross-XCD cost).
// Channel c runs 1 diagonal behind c-1. Depth-2 ring per channel:
//   channel c at time t (diag d=t-c) writes RING[c][d&1], reads own RING[c][(d-1)&1]
//   (phA/h2A) and producer RING[c-1][d&1] (po) -- written by c-1 at t-1, overwritten
//   only at t+1, so one barrier per step is sufficient.
// Register budget (<=256 so two waves share a SIMD): Wph/Wadp are streamed from LDS;
// r/z gate gi+gh fused into one MFMA-chained accumulator (biases pre-combined).
__global__ __launch_bounds__(384, 1)
void recur_all_kernel(const int* __restrict__ x, float* __restrict__ wsf)
{
  // single LDS object so the compiler cannot hoist the loop-invariant weight-frag
  // reads into persistent VGPRs (in-loop runtime-offset stores alias them).
  __shared__ __align__(16) short lds[12288 + 12288 + 9216 + 6144];   // 78 KB
  short* RING  = lds;            // [3][2][64][32] bf16 layer-2 outputs, slot = diag&1
  short* H01   = lds + 12288;    // [3][64][2][32] bf16 layer-0/1 hidden
  short* WPHL  = lds + 24576;    // [3][96][32]    bf16 Wph
  short* WADPL = lds + 33792;    // [2][96][32]    bf16 Wadp

  const int tid  = threadIdx.x;
  const int b    = blockIdx.x;
  const int wave = tid >> 6;
  const int c    = wave >> 1;        // channel
  const int hw   = wave & 1;         // row half
  const int lane = tid & 63;
  const int m    = lane & 15;        // A-frag row / C col
  const int q    = lane >> 4;        // quad
  const int ln   = m;

  // ---- stage LDS: zero state, bf16 copies of Wph/Wadp ----
  for (int i = tid; i < 12288 + 12288; i += 384) lds[i] = 0;
  for (int i = tid; i < 3*kG*kH; i += 384) WPHL[i]  = f2b(wsf[WPH_OFF + i]);
  for (int i = tid; i < 2*kG*kH; i += 384) WADPL[i] = f2b(wsf[WADP_OFF + i]);

  // ---- per-wave register weights: Whh0, Wih1, Whh1, Wih2, Whh2 (120 VGPRs) ----
  const float* wsrc[5];
  wsrc[0] = wsf + P_WHH  + (c*3+0)*kG*kH;
  wsrc[1] = wsf + P_WIHR + (c*2+0)*kG*kH;
  wsrc[2] = wsf + P_WHH  + (c*3+1)*kG*kH;
  wsrc[3] = wsf + P_WIHR + (c*2+1)*kG*kH;
  wsrc[4] = wsf + P_WHH  + (c*3+2)*kG*kH;
  bfrag Wr[5][6];
#pragma unroll
  for (int mt = 0; mt < 5; ++mt) {
#pragma unroll
    for (int u = 0; u < 6; ++u) {
      const float* p = wsrc[mt] + (u*16 + ln)*kH + q*8;
#pragma unroll
      for (int j = 0; j < 8; ++j) Wr[mt][u][j] = f2b(p[j]);
    }
  }

  // ---- per-lane gate constants; r/z tiles (u<4) carry gi+gh bias combined ----
  float rwt[6], c0tz[4], bi1z[4], bi2z[4];
  float c0n[2], bh0n[2], bi1n[2], bh1n[2], bi2n[2], bh2n[2];
#pragma unroll
  for (int u = 0; u < 6; ++u) rwt[u] = wsf[RW_OFF + c*kG + u*16 + ln];
#pragma unroll
  for (int u = 0; u < 4; ++u) {
    int g = u*16 + ln;
    c0tz[u] = wsf[C0_OFF + c*kG + g] + wsf[P_BHH + (c*3+0)*kG + g];
    bi1z[u] = wsf[P_BIH + (c*3+1)*kG + g] + wsf[P_BHH + (c*3+1)*kG + g];
    bi2z[u] = wsf[P_BIH + (c*3+2)*kG + g] + wsf[P_BHH + (c*3+2)*kG + g];
  }
#pragma unroll
  for (int t2 = 0; t2 < 2; ++t2) {
    int g = 64 + t2*16 + ln;
    c0n[t2]  = wsf[C0_OFF + c*kG + g];
    bh0n[t2] = wsf[P_BHH + (c*3+0)*kG + g];
    bi1n[t2] = wsf[P_BIH + (c*3+1)*kG + g];
    bh1n[t2] = wsf[P_BHH + (c*3+1)*kG + g];
    bi2n[t2] = wsf[P_BIH + (c*3+2)*kG + g];
    bh2n[t2] = wsf[P_BHH + (c*3+2)*kG + g];
  }

  // fp32 elementwise GRU state: [chunk][cell(i)*2+th] = (cell q*4+i, hid th*16+ln)
  float h0s[2][8], h1s[2][8], h2s[2][8];
#pragma unroll
  for (int k = 0; k < 2; ++k)
#pragma unroll
    for (int i = 0; i < 8; ++i) { h0s[k][i] = 0.f; h1s[k][i] = 0.f; h2s[k][i] = 0.f; }

  unsigned short* outsC = (unsigned short*)wsf + (size_t)(c*kB + b) * (kR*kS*kH);
  const int* xc = x + (b*3 + c) * kR * kS;
  const float* Tc = wsf + T_OFF + (size_t)c * kV * kG;

  __syncthreads();

  constexpr int TT = kR + kS - 1 + 2;   // 129: channel c lags c-1 by 1 diagonal
  for (int t = 0; t < TT; ++t) {
    const int d = t - c;
    if (d >= 0 && d < kR + kS - 1) {
      const int ps = (d - 1) & 1;
      const int cs = d & 1;
#pragma unroll
      for (int k = 0; k < 2; ++k) {
        const int cb0 = hw*32 + k*16;
        if (d >= cb0 && d <= cb0 + 78) {
          // ---- cell metadata ----
          int rr[4], ssv[4], xi[4];
          bool act[4];
#pragma unroll
          for (int i = 0; i < 4; ++i) {
            rr[i]  = cb0 + q*4 + i;
            ssv[i] = d - rr[i];
            act[i] = ((unsigned)ssv[i]) < 64u;
            int scl = ssv[i] < 0 ? 0 : (ssv[i] > 63 ? 63 : ssv[i]);
            xi[i]  = xc[rr[i]*kS + scl];
          }
          const int row = cb0 + m;

          // ---- layer-0 A-fragments ----
          bfrag phA, h0A, poA;
          {
            int pr = row - 1;
            int prc = pr < 0 ? 0 : pr;
            phA = *(const bfrag*)&RING[((c*2 + ps)*kR + prc)*kH + q*8];
            if (pr < 0) {
#pragma unroll
              for (int j = 0; j < 8; ++j) phA[j] = 0;
            }
            h0A = *(const bfrag*)&H01[((c*kR + row)*2 + 0)*kH + q*8];
            if (c > 0)
              poA = *(const bfrag*)&RING[(((c-1)*2 + cs)*kR + row)*kH + q*8];
          }

          // ---- layer 0 ----
          ffrag rz[4], gn[2], hn[2];
#pragma unroll
          for (int u = 0; u < 4; ++u)
#pragma unroll
            for (int i = 0; i < 4; ++i) {
              float g = 0.f;
              if (act[i]) {
                float rp = (float)rr[i] * (2.0f/64.0f) - 1.0f;
                g = Tc[(size_t)xi[i]*kG + u*16 + ln] + rp*rwt[u] + c0tz[u];
              }
              rz[u][i] = g;
            }
#pragma unroll
          for (int t2 = 0; t2 < 2; ++t2)
#pragma unroll
            for (int i = 0; i < 4; ++i) {
              float g = 0.f;
              if (act[i]) {
                float rp = (float)rr[i] * (2.0f/64.0f) - 1.0f;
                g = Tc[(size_t)xi[i]*kG + (4+t2)*16 + ln] + rp*rwt[4+t2] + c0n[t2];
              }
              gn[t2][i] = g;
              hn[t2][i] = bh0n[t2];
            }
          {
            const short* wph = &WPHL[(c*kG + ln)*kH + q*8];
#pragma unroll
            for (int u = 0; u < 4; ++u)
              rz[u] = MFMA16(phA, *(const bfrag*)(wph + u*16*kH), rz[u]);
#pragma unroll
            for (int t2 = 0; t2 < 2; ++t2)
              gn[t2] = MFMA16(phA, *(const bfrag*)(wph + (4+t2)*16*kH), gn[t2]);
          }
          if (c > 0) {
            const short* wad = &WADPL[((c-1)*kG + ln)*kH + q*8];
#pragma unroll
            for (int u = 0; u < 4; ++u)
              rz[u] = MFMA16(poA, *(const bfrag*)(wad + u*16*kH), rz[u]);
#pragma unroll
            for (int t2 = 0; t2 < 2; ++t2)
              gn[t2] = MFMA16(poA, *(const bfrag*)(wad + (4+t2)*16*kH), gn[t2]);
          }
#pragma unroll
          for (int u = 0; u < 4; ++u)
            rz[u] = MFMA16(h0A, Wr[0][u], rz[u]);
#pragma unroll
          for (int t2 = 0; t2 < 2; ++t2)
            hn[t2] = MFMA16(h0A, Wr[0][4+t2], hn[t2]);

#pragma unroll
          for (int i = 0; i < 4; ++i)
#pragma unroll
            for (int th = 0; th < 2; ++th) {
              float rg = sigm(rz[th][i]);
              float zg = sigm(rz[2+th][i]);
              float ng = tanh_(gn[th][i] + rg*hn[th][i]);
              float h0v = (1.f - zg)*ng + zg*h0s[k][i*2+th];
              if (act[i]) {
                h0s[k][i*2+th] = h0v;
                H01[((c*kR + rr[i])*2 + 0)*kH + th*16 + ln] = f2b(h0v);
              }
            }
          bfrag h0An = *(const bfrag*)&H01[((c*kR + row)*2 + 0)*kH + q*8];

          // ---- layer 1 ----
          bfrag h1A = *(const bfrag*)&H01[((c*kR + row)*2 + 1)*kH + q*8];
          ffrag rz1[4], gn1[2], hn1[2];
#pragma unroll
          for (int u = 0; u < 4; ++u)
#pragma unroll
            for (int i = 0; i < 4; ++i) rz1[u][i] = bi1z[u];
#pragma unroll
          for (int t2 = 0; t2 < 2; ++t2)
#pragma unroll
            for (int i = 0; i < 4; ++i) { gn1[t2][i] = bi1n[t2]; hn1[t2][i] = bh1n[t2]; }
#pragma unroll
          for (int u = 0; u < 4; ++u) {
            rz1[u] = MFMA16(h0An, Wr[1][u], rz1[u]);
            rz1[u] = MFMA16(h1A,  Wr[2][u], rz1[u]);
          }
#pragma unroll
          for (int t2 = 0; t2 < 2; ++t2) {
            gn1[t2] = MFMA16(h0An, Wr[1][4+t2], gn1[t2]);
            hn1[t2] = MFMA16(h1A,  Wr[2][4+t2], hn1[t2]);
          }
#pragma unroll
          for (int i = 0; i < 4; ++i)
#pragma unroll
            for (int th = 0; th < 2; ++th) {
              float rg = sigm(rz1[th][i]);
              float zg = sigm(rz1[2+th][i]);
              float ng = tanh_(gn1[th][i] + rg*hn1[th][i]);
              float h1v = (1.f - zg)*ng + zg*h1s[k][i*2+th];
              if (act[i]) {
                h1s[k][i*2+th] = h1v;
                H01[((c*kR + rr[i])*2 + 1)*kH + th*16 + ln] = f2b(h1v);
              }
            }
          bfrag h1An = *(const bfrag*)&H01[((c*kR + row)*2 + 1)*kH + q*8];

          // ---- layer 2 ----
          bfrag h2A = *(const bfrag*)&RING[((c*2 + ps)*kR + row)*kH + q*8];
          if (m == d - cb0) {            // this A-row's cell has s==0 -> no left neighbor
#pragma unroll
            for (int j = 0; j < 8; ++j) h2A[j] = 0;
          }
          ffrag rz2[4], gn2[2], hn2[2];
#pragma unroll
          for (int u = 0; u < 4; ++u)
#pragma unroll
            for (int i = 0; i < 4; ++i) rz2[u][i] = bi2z[u];
#pragma unroll
          for (int t2 = 0; t2 < 2; ++t2)
#pragma unroll
            for (int i = 0; i < 4; ++i) { gn2[t2][i] = bi2n[t2]; hn2[t2][i] = bh2n[t2]; }
#pragma unroll
          for (int u = 0; u < 4; ++u) {
            rz2[u] = MFMA16(h1An, Wr[3][u], rz2[u]);
            rz2[u] = MFMA16(h2A,  Wr[4][u], rz2[u]);
          }
#pragma unroll
          for (int t2 = 0; t2 < 2; ++t2) {
            gn2[t2] = MFMA16(h1An, Wr[3][4+t2], gn2[t2]);
            hn2[t2] = MFMA16(h2A,  Wr[4][4+t2], hn2[t2]);
          }
#pragma unroll
          for (int i = 0; i < 4; ++i)
#pragma unroll
            for (int th = 0; th < 2; ++th) {
              float rg = sigm(rz2[th][i]);
              float zg = sigm(rz2[2+th][i]);
              float ng = tanh_(gn2[th][i] + rg*hn2[th][i]);
              float h2old = (ssv[i] == 0) ? 0.f : h2s[k][i*2+th];
              float h2v = (1.f - zg)*ng + zg*h2old;
              if (act[i]) {
                h2s[k][i*2+th] = h2v;
                short hb = f2b(h2v);
                RING[((c*2 + cs)*kR + rr[i])*kH + th*16 + ln] = hb;
                outsC[((size_t)rr[i]*kS + ssv[i])*kH + th*16 + ln] = (unsigned short)hb;
              }
            }
        }
      }
    }
    __syncthreads();   // publishes this diagonal's RING/H01 writes block-wide
  }
}

// ---------------- logits epilogue (fp32 output, unchanged, verified) ----------------
__global__ void logits_kernel(const int* __restrict__ target, const float* __restrict__ wsf,
                              float* __restrict__ out)
{
  int idx = blockIdx.x * 256 + threadIdx.x;
  if (idx >= 3*kB*kR*kS*kV) return;
  int v = idx % kV;
  int pos = idx / kV;
  int g = pos >> 12;
  int ch = g % 3;
  int b = g / 3;
  int rs = pos & 4095;
  const bf16* hv = (const bf16*)wsf + ((size_t)(ch*kB + b)*4096 + rs)*kH;
  float acc;
  const float* wv;
  if (ch == 0) {
    acc = wsf[P_REDB + v];
    wv = wsf + P_REDW + v*kH;
  } else if (ch == 1) {
    int tr = target[(b*3 + 0)*4096 + rs];
    acc = wsf[P_GREENB + v] + wsf[TG_OFF + tr*kV + v];
    wv = wsf + P_GREENW + v*(kH + kE);
  } else {
    int tr = target[(b*3 + 0)*4096 + rs];
    int tg = target[(b*3 + 1)*4096 + rs];
    acc = wsf[P_BLUEB + v] + wsf[TBR_OFF + tr*kV + v] + wsf[TBG_OFF + tg*kV + v];
    wv = wsf + P_BLUEW + v*(kH + 2*kE);
  }
#pragma unroll
  for (int k = 0; k < kH; ++k) acc = fmaf(wv[k], tof(hv[k]), acc);
  out[idx] = acc;
}

extern "C" void kernel_launch(void* const* d_in, const int* in_sizes, int n_in,
                              void* d_out, int out_size, void* d_ws, size_t ws_size,
                              hipStream_t stream)
{
  const int* x      = (const int*)d_in[0];
  const int* target = (const int*)d_in[1];
  float* wsf = (float*)d_ws;

  norm_kernel<<<16, 256, 0, stream>>>(d_in[2], d_in[3], d_in[4], d_in[5], d_in[6], d_in[7],
                                      d_in[8], d_in[9], d_in[10], d_in[11], d_in[12], d_in[13],
                                      d_in[14], d_in[15], d_in[16], d_in[17], wsf);
  const int prepN = 3*kV*kG + 3*kG*kH + 2*kG*kH + 3*kG + 3*kG + 3*kV*kV;
  prep_kernel<<<(prepN + 255)/256, 256, 0, stream>>>(wsf);
  recur_all_kernel<<<16, 384, 0, stream>>>(x, wsf);
  const int outN = 3*kB*kR*kS*kV;
  logits_kernel<<<(outN + 255)/256, 256, 0, stream>>>(target, wsf, (float*)d_out);
}

// Round 3
// 2833.900 us; speedup vs baseline: 1.2814x; 1.2814x over previous
//
#include <hip/hip_runtime.h>
#include <hip/hip_bf16.h>

using bf16 = __hip_bfloat16;
typedef __attribute__((ext_vector_type(8))) short bfrag;   // 8 bf16 (4 VGPRs)
typedef __attribute__((ext_vector_type(4))) float ffrag;   // 4 fp32 acc

constexpr int kH  = 32;    // hidden
constexpr int kE  = 64;    // embed
constexpr int kV  = 258;   // vocab
constexpr int kB  = 16;    // batch
constexpr int kR  = 64;    // rows
constexpr int kS  = 64;    // cols
constexpr int kG  = 96;    // 3*H
constexpr int kEP = 65;    // E+1

// ---------------- workspace layout (unchanged) ----------------
constexpr int H2_OFF   = (3*kB*kR*kS*kH)/2;
constexpr int PROG_OFF = H2_OFF;                      // legacy progress flags (unused now)
constexpr int T_OFF    = H2_OFF + kB*kR*kH;           // [3][258][96]  emb@Wih0[:, :64].T (+bias fold)
constexpr int WPH_OFF  = T_OFF + 3*kV*kG;             // [3][96][32]   Wih0 @ h2e_W  fold
constexpr int WADP_OFF = WPH_OFF + 3*kG*kH;           // [2][96][32]   Wih0 @ adp_W  fold
constexpr int C0_OFF   = WADP_OFF + 2*kG*kH;          // [3][96]
constexpr int RW_OFF   = C0_OFF + 3*kG;               // [3][96]
constexpr int TG_OFF   = RW_OFF + 3*kG;               // [258][258]
constexpr int TBR_OFF  = TG_OFF + kV*kV;              // [258][258]
constexpr int TBG_OFF  = TBR_OFF + kV*kV;             // [258][258]
constexpr int P_EMB    = TBG_OFF + kV*kV;
constexpr int P_WIH0   = P_EMB    + 3*kV*kE;
constexpr int P_WIHR   = P_WIH0   + 3*kG*kEP;
constexpr int P_WHH    = P_WIHR   + 3*2*kG*kH;
constexpr int P_BIH    = P_WHH    + 3*3*kG*kH;
constexpr int P_BHH    = P_BIH    + 3*3*kG;
constexpr int P_H2EW   = P_BHH    + 3*3*kG;
constexpr int P_H2EB   = P_H2EW   + 3*kEP*kH;
constexpr int P_ADPW   = P_H2EB   + 3*kEP;
constexpr int P_ADPB   = P_ADPW   + 2*kEP*kH;
constexpr int P_REDW   = P_ADPB   + 2*kEP;
constexpr int P_REDB   = P_REDW   + kV*kH;
constexpr int P_GREENW = P_REDB   + kV;
constexpr int P_GREENB = P_GREENW + kV*(kH+kE);
constexpr int P_BLUEW  = P_GREENB + kV;
constexpr int P_BLUEB  = P_BLUEW  + kV*(kH+2*kE);
constexpr int WS_END   = P_BLUEB  + kV;               // ~14.0 MB

__device__ __forceinline__ float tof(bf16 h) { return __bfloat162float(h); }

__device__ __forceinline__ unsigned short bfbits(bf16 h) {
  union { bf16 h; unsigned short u; } cv; cv.h = h; return cv.u;
}
__device__ __forceinline__ short f2b(float v) {
  return (short)bfbits(__float2bfloat16(v));
}
__device__ __forceinline__ float sigm(float v) { return 1.0f / (1.0f + __expf(-v)); }
__device__ __forceinline__ float tanh_(float v) { return 1.0f - 2.0f / (__expf(2.0f * v) + 1.0f); }

#define MFMA16(a, bb, cc) __builtin_amdgcn_mfma_f32_16x16x32_bf16((a), (bb), (cc), 0, 0, 0)

// ---------------- dtype detect + normalize to fp32 (unchanged, verified) ----------------
__global__ void norm_kernel(const void* p0, const void* p1, const void* p2, const void* p3,
                            const void* p4, const void* p5, const void* p6, const void* p7,
                            const void* p8, const void* p9, const void* p10, const void* p11,
                            const void* p12, const void* p13, const void* p14, const void* p15,
                            float* __restrict__ wsf)
{
  constexpr int counts[16] = {3*kV*kE, 3*kG*kEP, 3*2*kG*kH, 3*3*kG*kH, 3*3*kG, 3*3*kG,
                              3*kEP*kH, 3*kEP, 2*kEP*kH, 2*kEP, kV*kH, kV,
                              kV*(kH+kE), kV, kV*(kH+2*kE), kV};
  constexpr int dsts[16] = {P_EMB, P_WIH0, P_WIHR, P_WHH, P_BIH, P_BHH,
                            P_H2EW, P_H2EB, P_ADPW, P_ADPB, P_REDW, P_REDB,
                            P_GREENW, P_GREENB, P_BLUEW, P_BLUEB};
  const void* srcs[16] = {p0,p1,p2,p3,p4,p5,p6,p7,p8,p9,p10,p11,p12,p13,p14,p15};

  __shared__ unsigned int smax;
  const int a = blockIdx.x;
  const void* src = srcs[a];
  const int n = counts[a];
  if (threadIdx.x == 0) smax = 0;
  if (a == 0) {
    int* prog = (int*)(wsf + PROG_OFF);
    for (int i = threadIdx.x; i < 48; i += 256) prog[i] = 0;
  }
  __syncthreads();

  const unsigned short* u16 = (const unsigned short*)src;
  const int ns = (n < 2048) ? n : 2048;
  unsigned int lm = 0;
  for (int i = threadIdx.x; i < ns; i += 256) {
    unsigned int e = ((unsigned int)u16[i] >> 7) & 0xFFu;
    if (e > lm) lm = e;
  }
  atomicMax(&smax, lm);
  __syncthreads();

  const bool isf32 = (smax >= 135);
  float* dst = wsf + dsts[a];
  if (isf32) {
    const float* s = (const float*)src;
    for (int i = threadIdx.x; i < n; i += 256) dst[i] = s[i];
  } else {
    const bf16* s = (const bf16*)src;
    for (int i = threadIdx.x; i < n; i += 256) dst[i] = tof(s[i]);
  }
}

// ---------------- prep: fold tables & matrices (unchanged, verified) ----------------
__global__ void prep_kernel(float* __restrict__ wsf)
{
  int idx = blockIdx.x * 256 + threadIdx.x;

  if (idx < 3*kV*kG) {
    int c = idx / (kV*kG);
    int rem = idx - c*(kV*kG);
    int v = rem / kG;
    int j = rem - v*kG;
    const float* ev = wsf + P_EMB + (c*kV + v)*kE;
    const float* wr = wsf + P_WIH0 + (c*kG + j)*kEP;
    float acc = 0.f;
    for (int e = 0; e < kE; ++e) acc = fmaf(ev[e], wr[e], acc);
    wsf[T_OFF + idx] = acc;
    return;
  }
  idx -= 3*kV*kG;

  if (idx < 3*kG*kH) {
    int c = idx / (kG*kH);
    int rem = idx - c*(kG*kH);
    int j = rem >> 5;
    int k = rem & 31;
    const float* wr = wsf + P_WIH0 + (c*kG + j)*kEP;
    const float* hw = wsf + P_H2EW + c*kEP*kH + k;
    float acc = 0.f;
    for (int e = 0; e < kEP; ++e) acc = fmaf(wr[e], hw[e*kH], acc);
    wsf[WPH_OFF + idx] = acc;
    return;
  }
  idx -= 3*kG*kH;

  if (idx < 2*kG*kH) {
    int cm = idx / (kG*kH);
    int rem = idx - cm*(kG*kH);
    int j = rem >> 5;
    int k = rem & 31;
    const float* wr = wsf + P_WIH0 + ((cm+1)*kG + j)*kEP;
    const float* aw = wsf + P_ADPW + cm*kEP*kH + k;
    float acc = 0.f;
    for (int e = 0; e < kEP; ++e) acc = fmaf(wr[e], aw[e*kH], acc);
    wsf[WADP_OFF + idx] = acc;
    return;
  }
  idx -= 2*kG*kH;

  if (idx < 3*kG) {
    int c = idx / kG;
    int j = idx - c*kG;
    const float* wr = wsf + P_WIH0 + (c*kG + j)*kEP;
    float acc = wsf[P_BIH + (c*3 + 0)*kG + j];
    for (int e = 0; e < kEP; ++e) acc = fmaf(wsf[P_H2EB + c*kEP + e], wr[e], acc);
    if (c > 0)
      for (int e = 0; e < kEP; ++e) acc = fmaf(wsf[P_ADPB + (c-1)*kEP + e], wr[e], acc);
    wsf[C0_OFF + idx] = acc;
    return;
  }
  idx -= 3*kG;

  if (idx < 3*kG) {
    int c = idx / kG;
    int j = idx - c*kG;
    wsf[RW_OFF + idx] = wsf[P_WIH0 + (c*kG + j)*kEP + kE];
    return;
  }
  idx -= 3*kG;

  if (idx < kV*kV) {
    int v = idx / kV, w = idx - (idx / kV)*kV;
    const float* ev = wsf + P_EMB + v*kE;
    const float* gw = wsf + P_GREENW + w*(kH + kE) + kH;
    float acc = 0.f;
    for (int e = 0; e < kE; ++e) acc = fmaf(ev[e], gw[e], acc);
    wsf[TG_OFF + idx] = acc;
    return;
  }
  idx -= kV*kV;

  if (idx < kV*kV) {
    int v = idx / kV, w = idx - (idx / kV)*kV;
    const float* ev = wsf + P_EMB + v*kE;
    const float* bw = wsf + P_BLUEW + w*(kH + 2*kE) + kH;
    float acc = 0.f;
    for (int e = 0; e < kE; ++e) acc = fmaf(ev[e], bw[e], acc);
    wsf[TBR_OFF + idx] = acc;
    return;
  }
  idx -= kV*kV;

  if (idx < kV*kV) {
    int v = idx / kV, w = idx - (idx / kV)*kV;
    const float* ev = wsf + P_EMB + (kV + v)*kE;
    const float* bw = wsf + P_BLUEW + w*(kH + 2*kE) + kH + kE;
    float acc = 0.f;
    for (int e = 0; e < kE; ++e) acc = fmaf(ev[e], bw[e], acc);
    wsf[TBG_OFF + idx] = acc;
  }
}

// ---------------- fold layer-0 gate constants into T ----------------
// T[c][v][g] += C0[c][g] + (g < 64 ? BHH0[c][g] : 0)
// r/z gates absorb the full gi+gh bias; n gate absorbs C0 only (its BHH0 part
// stays inside the r-scaled hn term).
__global__ void tfold_kernel(float* __restrict__ wsf)
{
  int idx = blockIdx.x * 256 + threadIdx.x;
  if (idx >= 3*kV*kG) return;
  int c = idx / (kV*kG);
  int g = idx % kG;
  float add = wsf[C0_OFF + c*kG + g];
  if (g < 2*kH) add += wsf[P_BHH + (c*3 + 0)*kG + g];
  wsf[T_OFF + idx] += add;
}

// ---------------- fused 3-channel wavefront recurrence: 12 waves / block ----------------
// Grid = 16 blocks (one per batch). Block = 768 = 12 waves: wave = c*4 + w.
// 3 waves/SIMD fills the exposed-latency stalls that dominated rounds 0-1
// (per-chunk serial cost ~10us at 1 wave/SIMD was pure instruction latency,
// round-1 A/B: step time doubled with chunks/wave, fence cost was negligible).
// LDS-only handoff, 1 uniform barrier/step, no atomics/spin-waits.
// VGPR cap 168 (3 waves/EU): only Whh0 in registers; other weights stream from
// LDS as bf16 B-frags (contiguous-1KB wave reads, conflict-free). H01 laid out
// [ch][layer][row][32] to kill the old 16-way A-frag read bank conflict.
__global__ __launch_bounds__(768, 3)
void recur_all_kernel(const int* __restrict__ x, float* __restrict__ wsf)
{
  __shared__ __align__(16) short lds[12288 + 12288 + 17*kG*kH];   // 150 KB
  short* RING = lds;            // [3][2][64][32] layer-2 outputs, slot = diag&1
  short* H01  = lds + 12288;    // [3][2(layer)][64][32]
  short* WL   = lds + 24576;    // [17][96][32] weight B-frags (bf16)

  const int tid  = threadIdx.x;
  const int b    = blockIdx.x;
  const int wave = tid >> 6;
  const int c    = wave >> 2;        // channel
  const int w    = wave & 3;         // 16-row band
  const int lane = tid & 63;
  const int m    = lane & 15;
  const int q    = lane >> 4;
  const int ln   = m;
  const int cb0  = w * 16;

  for (int i = tid; i < 24576; i += 768) lds[i] = 0;

  // mats: 0..2 Wph[c]; 3..4 Wadp[cm]; 5..7 Wih1[c]; 8..10 Whh1[c]; 11..13 Wih2[c]; 14..16 Whh2[c]
#pragma unroll
  for (int mat = 0; mat < 17; ++mat) {
    const int off = (mat < 3)  ? WPH_OFF + mat*kG*kH
                  : (mat < 5)  ? WADP_OFF + (mat-3)*kG*kH
                  : (mat < 8)  ? P_WIHR + ((mat-5)*2 + 0)*kG*kH
                  : (mat < 11) ? P_WHH  + ((mat-8)*3 + 1)*kG*kH
                  : (mat < 14) ? P_WIHR + ((mat-11)*2 + 1)*kG*kH
                  :              P_WHH  + ((mat-14)*3 + 2)*kG*kH;
    for (int j = tid; j < kG*kH; j += 768)
      WL[mat*kG*kH + j] = f2b(wsf[off + j]);
  }

  // ---- Whh0 B-frags in registers (24 VGPRs) ----
  bfrag Wr0[6];
  {
    const float* whh0 = wsf + P_WHH + (c*3 + 0)*kG*kH;
#pragma unroll
    for (int u = 0; u < 6; ++u) {
      const float* p = whh0 + (u*16 + ln)*kH + q*8;
#pragma unroll
      for (int j = 0; j < 8; ++j) Wr0[u][j] = f2b(p[j]);
    }
  }

  // ---- per-lane gate constants (layer-0 c0 terms folded into T) ----
  float rwt[6], bh0n[2], bi1z[4], bi1n[2], bh1n[2], bi2z[4], bi2n[2], bh2n[2];
#pragma unroll
  for (int u = 0; u < 6; ++u) rwt[u] = wsf[RW_OFF + c*kG + u*16 + ln];
#pragma unroll
  for (int u = 0; u < 4; ++u) {
    int g = u*16 + ln;
    bi1z[u] = wsf[P_BIH + (c*3+1)*kG + g] + wsf[P_BHH + (c*3+1)*kG + g];
    bi2z[u] = wsf[P_BIH + (c*3+2)*kG + g] + wsf[P_BHH + (c*3+2)*kG + g];
  }
#pragma unroll
  for (int t2 = 0; t2 < 2; ++t2) {
    int g = 64 + t2*16 + ln;
    bh0n[t2] = wsf[P_BHH + (c*3+0)*kG + g];
    bi1n[t2] = wsf[P_BIH + (c*3+1)*kG + g];
    bh1n[t2] = wsf[P_BHH + (c*3+1)*kG + g];
    bi2n[t2] = wsf[P_BIH + (c*3+2)*kG + g];
    bh2n[t2] = wsf[P_BHH + (c*3+2)*kG + g];
  }

  float h0s[8], h1s[8], h2s[8];
#pragma unroll
  for (int i = 0; i < 8; ++i) { h0s[i] = 0.f; h1s[i] = 0.f; h2s[i] = 0.f; }

  const short* wphL = WL + (c)*kG*kH               + ln*32 + q*8;   // + u*512
  const short* wadL = WL + (3 + (c>0?c-1:0))*kG*kH + ln*32 + q*8;
  const short* wi1L = WL + (5 + c)*kG*kH           + ln*32 + q*8;
  const short* wh1L = WL + (8 + c)*kG*kH           + ln*32 + q*8;
  const short* wi2L = WL + (11 + c)*kG*kH          + ln*32 + q*8;
  const short* wh2L = WL + (14 + c)*kG*kH          + ln*32 + q*8;
#define BFR(base, u) (*(const bfrag*)((base) + (u)*512))

  short* ringc = RING + c*2*2048;                       // [2][64][32]
  const short* ringp = RING + (c>0 ? c-1 : 0)*2*2048;
  short* h0pl = H01 + (c*2 + 0)*2048;
  short* h1pl = H01 + (c*2 + 1)*2048;

  unsigned short* outsC = (unsigned short*)wsf + (size_t)(c*kB + b) * (kR*kS*kH);
  const int* xc = x + (b*3 + c) * kR * kS;
  const float* Tc = wsf + T_OFF + (size_t)c * kV * kG;

  __syncthreads();

  constexpr int TT = kR + kS - 1 + 2;   // 129
  for (int t = 0; t < TT; ++t) {
    const int d = t - c;
    if (d >= cb0 && d <= cb0 + 78) {
      const int ps = (d - 1) & 1;
      const int cs = d & 1;

      int rr[4], ssv[4], xi[4];
      bool act[4];
#pragma unroll
      for (int i = 0; i < 4; ++i) {
        rr[i]  = cb0 + q*4 + i;
        ssv[i] = d - rr[i];
        act[i] = ((unsigned)ssv[i]) < 64u;
        int scl = ssv[i] < 0 ? 0 : (ssv[i] > 63 ? 63 : ssv[i]);
        xi[i]  = xc[rr[i]*kS + scl];
      }
      const int row = cb0 + m;

      bfrag phA, h0A, poA;
      {
        int pr = row - 1;
        int prc = pr < 0 ? 0 : pr;
        phA = *(const bfrag*)&RING[(c*2 + ps)*2048 + prc*32 + q*8];
        if (pr < 0) {
#pragma unroll
          for (int j = 0; j < 8; ++j) phA[j] = 0;
        }
        h0A = *(const bfrag*)&h0pl[row*32 + q*8];
        if (c > 0)
          poA = *(const bfrag*)&ringp[cs*2048 + row*32 + q*8];
      }

      // ---- layer 0 ----
      ffrag rz[4], gn[2], hn[2];
#pragma unroll
      for (int u = 0; u < 4; ++u)
#pragma unroll
        for (int i = 0; i < 4; ++i) {
          float g = 0.f;
          if (act[i]) {
            float rp = (float)rr[i] * (2.0f/64.0f) - 1.0f;
            g = Tc[(size_t)xi[i]*kG + u*16 + ln] + rp*rwt[u];
          }
          rz[u][i] = g;
        }
#pragma unroll
      for (int t2 = 0; t2 < 2; ++t2)
#pragma unroll
        for (int i = 0; i < 4; ++i) {
          float g = 0.f;
          if (act[i]) {
            float rp = (float)rr[i] * (2.0f/64.0f) - 1.0f;
            g = Tc[(size_t)xi[i]*kG + (4+t2)*16 + ln] + rp*rwt[4+t2];
          }
          gn[t2][i] = g;
          hn[t2][i] = bh0n[t2];
        }
#pragma unroll
      for (int u = 0; u < 4; ++u)
        rz[u] = MFMA16(phA, BFR(wphL, u), rz[u]);
#pragma unroll
      for (int t2 = 0; t2 < 2; ++t2)
        gn[t2] = MFMA16(phA, BFR(wphL, 4+t2), gn[t2]);
      if (c > 0) {
#pragma unroll
        for (int u = 0; u < 4; ++u)
          rz[u] = MFMA16(poA, BFR(wadL, u), rz[u]);
#pragma unroll
        for (int t2 = 0; t2 < 2; ++t2)
          gn[t2] = MFMA16(poA, BFR(wadL, 4+t2), gn[t2]);
      }
#pragma unroll
      for (int u = 0; u < 4; ++u)
        rz[u] = MFMA16(h0A, Wr0[u], rz[u]);
#pragma unroll
      for (int t2 = 0; t2 < 2; ++t2)
        hn[t2] = MFMA16(h0A, Wr0[4+t2], hn[t2]);

#pragma unroll
      for (int i = 0; i < 4; ++i)
#pragma unroll
        for (int th = 0; th < 2; ++th) {
          float rg = sigm(rz[th][i]);
          float zg = sigm(rz[2+th][i]);
          float ng = tanh_(gn[th][i] + rg*hn[th][i]);
          float h0v = (1.f - zg)*ng + zg*h0s[i*2+th];
          if (act[i]) {
            h0s[i*2+th] = h0v;
            h0pl[rr[i]*32 + th*16 + ln] = f2b(h0v);
          }
        }
      bfrag h0An = *(const bfrag*)&h0pl[row*32 + q*8];

      // ---- layer 1 ----
      bfrag h1A = *(const bfrag*)&h1pl[row*32 + q*8];
      ffrag rz1[4], gn1[2], hn1[2];
#pragma unroll
      for (int u = 0; u < 4; ++u)
#pragma unroll
        for (int i = 0; i < 4; ++i) rz1[u][i] = bi1z[u];
#pragma unroll
      for (int t2 = 0; t2 < 2; ++t2)
#pragma unroll
        for (int i = 0; i < 4; ++i) { gn1[t2][i] = bi1n[t2]; hn1[t2][i] = bh1n[t2]; }
#pragma unroll
      for (int u = 0; u < 4; ++u) {
        rz1[u] = MFMA16(h0An, BFR(wi1L, u), rz1[u]);
        rz1[u] = MFMA16(h1A,  BFR(wh1L, u), rz1[u]);
      }
#pragma unroll
      for (int t2 = 0; t2 < 2; ++t2) {
        gn1[t2] = MFMA16(h0An, BFR(wi1L, 4+t2), gn1[t2]);
        hn1[t2] = MFMA16(h1A,  BFR(wh1L, 4+t2), hn1[t2]);
      }
#pragma unroll
      for (int i = 0; i < 4; ++i)
#pragma unroll
        for (int th = 0; th < 2; ++th) {
          float rg = sigm(rz1[th][i]);
          float zg = sigm(rz1[2+th][i]);
          float ng = tanh_(gn1[th][i] + rg*hn1[th][i]);
          float h1v = (1.f - zg)*ng + zg*h1s[i*2+th];
          if (act[i]) {
            h1s[i*2+th] = h1v;
            h1pl[rr[i]*32 + th*16 + ln] = f2b(h1v);
          }
        }
      bfrag h1An = *(const bfrag*)&h1pl[row*32 + q*8];

      // ---- layer 2 ----
      bfrag h2A = *(const bfrag*)&ringc[ps*2048 + row*32 + q*8];
      if (m == d - cb0) {            // this A-row's cell has s==0 -> no left neighbor
#pragma unroll
        for (int j = 0; j < 8; ++j) h2A[j] = 0;
      }
      ffrag rz2[4], gn2[2], hn2[2];
#pragma unroll
      for (int u = 0; u < 4; ++u)
#pragma unroll
        for (int i = 0; i < 4; ++i) rz2[u][i] = bi2z[u];
#pragma unroll
      for (int t2 = 0; t2 < 2; ++t2)
#pragma unroll
        for (int i = 0; i < 4; ++i) { gn2[t2][i] = bi2n[t2]; hn2[t2][i] = bh2n[t2]; }
#pragma unroll
      for (int u = 0; u < 4; ++u) {
        rz2[u] = MFMA16(h1An, BFR(wi2L, u), rz2[u]);
        rz2[u] = MFMA16(h2A,  BFR(wh2L, u), rz2[u]);
      }
#pragma unroll
      for (int t2 = 0; t2 < 2; ++t2) {
        gn2[t2] = MFMA16(h1An, BFR(wi2L, 4+t2), gn2[t2]);
        hn2[t2] = MFMA16(h2A,  BFR(wh2L, 4+t2), hn2[t2]);
      }
#pragma unroll
      for (int i = 0; i < 4; ++i)
#pragma unroll
        for (int th = 0; th < 2; ++th) {
          float rg = sigm(rz2[th][i]);
          float zg = sigm(rz2[2+th][i]);
          float ng = tanh_(gn2[th][i] + rg*hn2[th][i]);
          float h2old = (ssv[i] == 0) ? 0.f : h2s[i*2+th];
          float h2v = (1.f - zg)*ng + zg*h2old;
          if (act[i]) {
            h2s[i*2+th] = h2v;
            short hb = f2b(h2v);
            ringc[cs*2048 + rr[i]*32 + th*16 + ln] = hb;
            outsC[((size_t)rr[i]*kS + ssv[i])*kH + th*16 + ln] = (unsigned short)hb;
          }
        }
    }
    __syncthreads();
  }
#undef BFR
}

// ---------------- logits epilogue (fp32 output, unchanged, verified) ----------------
__global__ void logits_kernel(const int* __restrict__ target, const float* __restrict__ wsf,
                              float* __restrict__ out)
{
  int idx = blockIdx.x * 256 + threadIdx.x;
  if (idx >= 3*kB*kR*kS*kV) return;
  int v = idx % kV;
  int pos = idx / kV;
  int g = pos >> 12;
  int ch = g % 3;
  int b = g / 3;
  int rs = pos & 4095;
  const bf16* hv = (const bf16*)wsf + ((size_t)(ch*kB + b)*4096 + rs)*kH;
  float acc;
  const float* wv;
  if (ch == 0) {
    acc = wsf[P_REDB + v];
    wv = wsf + P_REDW + v*kH;
  } else if (ch == 1) {
    int tr = target[(b*3 + 0)*4096 + rs];
    acc = wsf[P_GREENB + v] + wsf[TG_OFF + tr*kV + v];
    wv = wsf + P_GREENW + v*(kH + kE);
  } else {
    int tr = target[(b*3 + 0)*4096 + rs];
    int tg = target[(b*3 + 1)*4096 + rs];
    acc = wsf[P_BLUEB + v] + wsf[TBR_OFF + tr*kV + v] + wsf[TBG_OFF + tg*kV + v];
    wv = wsf + P_BLUEW + v*(kH + 2*kE);
  }
#pragma unroll
  for (int k = 0; k < kH; ++k) acc = fmaf(wv[k], tof(hv[k]), acc);
  out[idx] = acc;
}

extern "C" void kernel_launch(void* const* d_in, const int* in_sizes, int n_in,
                              void* d_out, int out_size, void* d_ws, size_t ws_size,
                              hipStream_t stream)
{
  const int* x      = (const int*)d_in[0];
  const int* target = (const int*)d_in[1];
  float* wsf = (float*)d_ws;

  norm_kernel<<<16, 256, 0, stream>>>(d_in[2], d_in[3], d_in[4], d_in[5], d_in[6], d_in[7],
                                      d_in[8], d_in[9], d_in[10], d_in[11], d_in[12], d_in[13],
                                      d_in[14], d_in[15], d_in[16], d_in[17], wsf);
  const int prepN = 3*kV*kG + 3*kG*kH + 2*kG*kH + 3*kG + 3*kG + 3*kV*kV;
  prep_kernel<<<(prepN + 255)/256, 256, 0, stream>>>(wsf);
  tfold_kernel<<<(3*kV*kG + 255)/256, 256, 0, stream>>>(wsf);
  recur_all_kernel<<<16, 768, 0, stream>>>(x, wsf);
  const int outN = 3*kB*kR*kS*kV;
  logits_kernel<<<(outN + 255)/256, 256, 0, stream>>>(target, wsf, (float*)d_out);
}